// Round 16
// baseline (192.828 us; speedup 1.0000x reference)
//
#include <hip/hip_runtime.h>

#define DD 256
#define NH 8
#define HPT 2    // heads per thread
#define NHG 4    // head-groups (threads per row)

constexpr float LN_EPS = 1e-5f;
constexpr float SCALE  = 0.0625f;         // 1/sqrt(256)
// Scaled-Schraudolph, KS folded into per-head constants:
//   dh = (aq*KS)*x_j + (c*KS); NR-rcp(|dh|) = 2^23*log2e/|d_raw| is DIRECTLY
//   the exp bit-argument. sW accumulates RAW x_j.
constexpr float KS     = 8.2629579e-8f;   // ln2 / 2^23
constexpr float B_EXP  = 1064986816.0f;   // 2^23 * (127 - 0.0436775)
// T = 12 ln-units (validated R13-R15: absmax 0.0078).
constexpr float T0     = 1.36150e8f;      // 0.9375 * 12 * 12102203
#define RCP_MAGIC 0x7EF311C3u

// weight = bits-exp of (rcp|dh| - m), CLAMPED at B_EXP (NR mis-order -> max
// weight = correct tie; NaN corner absorbed). cvt saturates neg/NaN -> 0.
__device__ __forceinline__ float wexp_clamped(float dh, float Bh) {
    float y = __uint_as_float(RCP_MAGIC - __float_as_uint(dh));
    float w = fmaf(-fabsf(dh), fabsf(y), 2.0f);
    float f = fminf(fmaf(fabsf(y), w, Bh), B_EXP);
    unsigned u;
    asm("v_cvt_u32_f32 %0, %1" : "=v"(u) : "v"(f));
    return __uint_as_float(u);
}

// branchless search over 256 near-sorted floats; returns p in [0,255].
__device__ __forceinline__ int lb256(const float* __restrict__ a, float t) {
    int p = 0;
    #pragma unroll
    for (int st = 128; st > 0; st >>= 1)
        p += (a[p + st - 1] < t) ? st : 0;
    return p;
}

// order-preserving float->uint32 (total order = float order)
__device__ __forceinline__ unsigned f2s(float f) {
    unsigned u = __float_as_uint(f);
    return (u & 0x80000000u) ? ~u : (u | 0x80000000u);
}

struct HeadCtx { float Bh; int cLo, cHi; };

// Window bounds for one (rank,head) context (R14/R15-validated logic).
__device__ __forceinline__ HeadCtx fla_bounds(const float* __restrict__ xsrt,
                                              float aqk, float ck) {
    float inv_aqk = __builtin_amdgcn_rcpf(aqk);
    float xstar = fminf(fmaxf(-ck * inv_aqk, -1e5f), 1e5f);   // NaN/inf guard
    int pos = lb256(xsrt, xstar);
    pos += (xsrt[pos] < xstar) ? 1 : 0;
    int i1 = (pos - 1 > 0) ? pos - 1 : 0;
    int i2 = (pos < DD - 1) ? pos : DD - 1;
    float x2 = xsrt[i2];
    float d1 = fabsf(fmaf(aqk, xsrt[i1], ck));
    float d2 = fabsf(fmaf(aqk, x2, ck));
    float dm = fminf(d1, d2);
    float ym = __uint_as_float(RCP_MAGIC - __float_as_uint(dm));
    float m  = fabsf(ym) * fmaf(-dm, fabsf(ym), 2.0f);
    float mm = fmaf(m, 0.9375f, -T0);         // >0 => truncation window valid
    float halfw = (mm > 0.f) ? __builtin_amdgcn_rcpf(mm) * fabsf(inv_aqk)
                             : 3e38f;
    float vlo = xstar - halfw;
    float vhi = fmaxf(xstar + halfw, x2);
    int lo = lb256(xsrt, vlo); lo = (lo < i1) ? lo : i1;
    int hi = lb256(xsrt, vhi); hi += (xsrt[hi] < vhi) ? 1 : 0;
    hi = (hi > i2 + 1) ? hi : i2 + 1;
    HeadCtx h; h.Bh = B_EXP - m; h.cLo = lo >> 2; h.cHi = (hi - 1) >> 2;
    return h;
}

// Chunked scan with PRECOMPUTED bounds (pipelined ds_read_b128).
__device__ __forceinline__ float2 fla_scan(const float* __restrict__ xsrt,
                                           float aqk, float ck, HeadCtx hc) {
    const float4* xs4 = reinterpret_cast<const float4*>(xsrt);
    float sE0=0.f,sE1=0.f,sE2=0.f,sE3=0.f;
    float sW0=0.f,sW1=0.f,sW2=0.f,sW3=0.f;
    #pragma unroll 2
    for (int ci = hc.cLo; ci <= hc.cHi; ++ci) {
        float4 xj = xs4[ci];
        float e0 = wexp_clamped(fmaf(aqk, xj.x, ck), hc.Bh);
        float e1 = wexp_clamped(fmaf(aqk, xj.y, ck), hc.Bh);
        float e2 = wexp_clamped(fmaf(aqk, xj.z, ck), hc.Bh);
        float e3 = wexp_clamped(fmaf(aqk, xj.w, ck), hc.Bh);
        sE0 += e0; sW0 = fmaf(e0, xj.x, sW0);
        sE1 += e1; sW1 = fmaf(e1, xj.y, sW1);
        sE2 += e2; sW2 = fmaf(e2, xj.z, sW2);
        sE3 += e3; sW3 = fmaf(e3, xj.w, sW3);
    }
    return make_float2((sE0+sE1)+(sE2+sE3), (sW0+sW1)+(sW2+sW3));
}

// Reduce two values across a 1024-thread block (16 waves). All threads get it.
__device__ __forceinline__ float2 block_reduce2(float a, float b, float* sc, int tid) {
    #pragma unroll
    for (int off = 32; off; off >>= 1) {
        a += __shfl_down(a, off, 64);
        b += __shfl_down(b, off, 64);
    }
    __syncthreads();                      // protect sc from previous use
    if ((tid & 63) == 0) { int w = tid >> 6; sc[w] = a; sc[16 + w] = b; }
    __syncthreads();
    const float4* s4 = reinterpret_cast<const float4*>(sc);
    float4 a0 = s4[0], a1 = s4[1], a2 = s4[2], a3 = s4[3];
    float4 b0 = s4[4], b1 = s4[5], b2 = s4[6], b3 = s4[7];
    float ra = ((a0.x+a0.y)+(a0.z+a0.w)) + ((a1.x+a1.y)+(a1.z+a1.w))
             + ((a2.x+a2.y)+(a2.z+a2.w)) + ((a3.x+a3.y)+(a3.z+a3.w));
    float rb = ((b0.x+b0.y)+(b0.z+b0.w)) + ((b1.x+b1.y)+(b1.z+b1.w))
             + ((b2.x+b2.y)+(b2.z+b2.w)) + ((b3.x+b3.y)+(b3.z+b3.w));
    return make_float2(ra, rb);
}

// BOTH layers + final projection in ONE kernel: every op in this network is
// row-independent (FLA/LN/Linear/projection all mix only within a row), so
// the inter-layer dependency is block-local -> __syncthreads, not a second
// dispatch. Saves a launch gap, a dispatch ramp, and the ws HBM round-trip.
__global__ __launch_bounds__(1024, 8) void flann_fused(
    const float* __restrict__ x_in,     // [B, DD]
    const float* __restrict__ alphas,   // [L, NH, 3]
    const float* __restrict__ betas,    // [L, NH, 3]
    const float* __restrict__ g1a, const float* __restrict__ b1a,  // [L, DD]
    const float* __restrict__ Wa,  const float* __restrict__ wba,  // [L,DD,DD],[L,DD]
    const float* __restrict__ g2a, const float* __restrict__ b2a,  // [L, DD]
    const float* __restrict__ outW, const float* __restrict__ outB,
    float* __restrict__ out)            // [B]
{
    __shared__ __align__(16) float xorig[DD];       // original-order values
    __shared__ __align__(16) float xsrt[DD];        // key-sorted exact values
    __shared__ __align__(16) float xln[DD];         // LN1 out, then layer x-fer
    __shared__ unsigned karr[DD];                   // sorted 32-bit keys
    __shared__ float comb[NHG][DD];                 // sort scratch, acc, GEMM
    __shared__ float sc[32];

    const int tid  = threadIdx.x;
    const int i    = tid & (DD - 1);    // lane slot; orig row for epilogue
    const int hg   = tid >> 8;          // head-group 0..3 (heads 2hg, 2hg+1)
    const int bidx = blockIdx.x;

    float xv = x_in[bidx * DD + i];     // layer-0 input (original index i)

    #pragma unroll 1
    for (int l = 0; l < 2; ++l) {
        const float* alp = alphas + l * NH * 3;
        const float* bet = betas  + l * NH * 3;
        const float* g1  = g1a + l * DD;  const float* b1 = b1a + l * DD;
        const float* W   = Wa  + l * DD * DD;
        const float* wb  = wba + l * DD;
        const float* g2  = g2a + l * DD;  const float* b2 = b2a + l * DD;

        if (hg == 0) xorig[i] = xv;

        // ---- 32-bit key bitonic sort: (f2s(x) & ~0xFF) | orig_index ----
        // (8-bit mantissa truncation only permutes near-equal values; the
        //  window is index-clamped & inflated -> unaffected. R15-validated.)
        {
            unsigned v = (f2s(xv) & 0xFFFFFF00u) | (unsigned)i;
            unsigned* flat = reinterpret_cast<unsigned*>(&comb[0][0]);
            #pragma unroll
            for (int k = 2; k <= DD; k <<= 1) {
                #pragma unroll
                for (int j = k >> 1; j > 0; j >>= 1) {
                    unsigned p;
                    if (j < 64) {
                        p = (unsigned)__shfl_xor((int)v, j, 64);
                    } else {
                        flat[tid] = v;
                        __syncthreads();
                        p = flat[tid ^ j];
                        __syncthreads();
                    }
                    bool keepmin = (((i & j) == 0) == ((i & k) == 0));
                    v = keepmin ? (v < p ? v : p) : (v > p ? v : p);
                }
            }
            if (hg == 0) {              // lane holds rank-i key
                karr[i] = v;
                xsrt[i] = xorig[v & 0xFFu];
            }
            __syncthreads();
        }

        // ---- tail-fold rank assignment (dense tails -> 1 of 4 waves) ----
        const int r      = (i & 1) ? (DD - 1) - (i >> 1) : (i >> 1);
        const int idx_r  = (int)(karr[r] & 0xFFu);
        const float xr_v = xsrt[r];

        // ---- my 2 heads' params for the RANK-r context ----
        const int h0 = hg * HPT;
        const float aq0 = alp[h0*3+0], ak0 = alp[h0*3+1], av0 = alp[h0*3+2];
        const float bq0 = bet[h0*3+0], bk0 = bet[h0*3+1], bv0 = bet[h0*3+2];
        const float aq1 = alp[h0*3+3], ak1 = alp[h0*3+4], av1 = alp[h0*3+5];
        const float bq1 = bet[h0*3+3], bk1 = bet[h0*3+4], bv1 = bet[h0*3+5];
        const float aqk0 = aq0 * KS, aqk1 = aq1 * KS;
        const float ck0  = (bq0 - fmaf(ak0, xr_v, bk0)) * KS;
        const float ck1  = (bq1 - fmaf(ak1, xr_v, bk1)) * KS;

        // bounds for BOTH heads first (chains interleave), then both scans
        HeadCtx hc0 = fla_bounds(xsrt, aqk0, ck0);
        HeadCtx hc1 = fla_bounds(xsrt, aqk1, ck1);
        float2 s0 = fla_scan(xsrt, aqk0, ck0, hc0);
        float2 s1 = fla_scan(xsrt, aqk1, ck1, hc1);

        // sW in RAW x units -> no rescale. 1/sE via magic + 2 NR.
        float yE0 = __uint_as_float(RCP_MAGIC - __float_as_uint(s0.x));
        float rE0 = fabsf(yE0) * fmaf(-s0.x, fabsf(yE0), 2.0f);
        rE0 = rE0 * fmaf(-s0.x, rE0, 2.0f);
        float yE1 = __uint_as_float(RCP_MAGIC - __float_as_uint(s1.x));
        float rE1 = fabsf(yE1) * fmaf(-s1.x, fabsf(yE1), 2.0f);
        rE1 = rE1 * fmaf(-s1.x, rE1, 2.0f);
        float accp = fmaf(av0, s0.y, bv0 * s0.x) * rE0
                   + fmaf(av1, s1.y, bv1 * s1.x) * rE1;
        __syncthreads();                // comb's sort-scratch use is done
        comb[hg][idx_r] = accp;         // scatter back to ORIGINAL index
        __syncthreads();

        // ---- combine head-groups, residual + ReLU (hg 0, original i) ----
        float xr = 0.f;
        if (hg == 0) {
            float acc = (comb[0][i] + comb[1][i]) + (comb[2][i] + comb[3][i]);
            xr = fmaxf(fmaf(SCALE, acc, xv), 0.f);
        }

        // ---- LayerNorm 1 (hg!=0 contributes zeros) ----
        float2 rr = block_reduce2(xr, xr * xr, sc, tid);
        float mu  = rr.x * (1.f / DD);
        float var = rr.y * (1.f / DD) - mu * mu;
        if (hg == 0) {
            float xn = (xr - mu) * __builtin_amdgcn_rsqf(var + LN_EPS);
            xln[i] = fmaf(xn, g1[i], b1[i]);
        }
        __syncthreads();

        // ---- Linear: d-range split 4 ways across hg ----
        const float4* xl4 = reinterpret_cast<const float4*>(xln);
        float ga0 = (hg == 0) ? wb[i] : 0.f, ga1 = 0.f, ga2 = 0.f, ga3 = 0.f;
        #pragma unroll 4
        for (int d4 = 0; d4 < DD/16; ++d4) {
            int g4 = hg * (DD/16) + d4;
            float4 xd = xl4[g4];
            int dr = 4 * g4;
            ga0 = fmaf(xd.x, W[(dr + 0) * DD + i], ga0);   // coalesced in i
            ga1 = fmaf(xd.y, W[(dr + 1) * DD + i], ga1);
            ga2 = fmaf(xd.z, W[(dr + 2) * DD + i], ga2);
            ga3 = fmaf(xd.w, W[(dr + 3) * DD + i], ga3);
        }
        __syncthreads();                // xln reads done before comb rewrite
        comb[hg][i] = (ga0 + ga1) + (ga2 + ga3);
        __syncthreads();

        float gv = 0.f;
        if (hg == 0)
            gv = fmaxf((comb[0][i] + comb[1][i]) + (comb[2][i] + comb[3][i]), 0.f);

        // ---- LayerNorm 2 ----
        rr = block_reduce2(gv, gv * gv, sc, tid);   // internal barriers cover
        mu  = rr.x * (1.f / DD);                    // the comb reads above
        var = rr.y * (1.f / DD) - mu * mu;
        float xo = 0.f;
        if (hg == 0)
            xo = fmaf((gv - mu) * __builtin_amdgcn_rsqf(var + LN_EPS), g2[i], b2[i]);

        if (l == 0) {
            // hand layer-0 output to all head-groups via xln
            if (hg == 0) xln[i] = xo;
            __syncthreads();
            xv = xln[i];
            __syncthreads();            // xv read before layer-1 reuses xln
        } else {
            // final projection: out[b] = sum_d x[d]*outW[d] + outB
            float pr = (hg == 0) ? xo * outW[i] : 0.f;
            float2 p = block_reduce2(pr, 0.f, sc, tid);
            if (tid == 0) out[bidx] = p.x + outB[0];
        }
    }
}

extern "C" void kernel_launch(void* const* d_in, const int* in_sizes, int n_in,
                              void* d_out, int out_size, void* d_ws, size_t ws_size,
                              hipStream_t stream) {
    const float* x      = (const float*)d_in[0];
    const float* alphas = (const float*)d_in[1];   // [L, NH, 3]
    const float* betas  = (const float*)d_in[2];   // [L, NH, 3]
    const float* flag   = (const float*)d_in[3];   // [L, DD]
    const float* flab   = (const float*)d_in[4];
    const float* linW   = (const float*)d_in[5];   // [L, DD, DD]
    const float* linb   = (const float*)d_in[6];   // [L, DD]
    const float* ling   = (const float*)d_in[7];
    const float* linb2  = (const float*)d_in[8];
    const float* outW   = (const float*)d_in[9];   // [DD]
    const float* outB   = (const float*)d_in[10];  // [1]

    const int B = in_sizes[0] / DD;
    float* outp = (float*)d_out;       // [B]

    // single fused dispatch: both layers + projection, block-local handoff
    flann_fused<<<dim3(B), dim3(1024), 0, stream>>>(
        x, alphas, betas, flag, flab, linW, linb, ling, linb2,
        outW, outB, outp);
}

// Round 17
// 156.408 us; speedup vs baseline: 1.2329x; 1.2329x over previous
//
#include <hip/hip_runtime.h>

#define DD 256
#define NH 8
#define HPT 2    // heads per thread
#define NHG 4    // head-groups (threads per row)

constexpr float LN_EPS = 1e-5f;
constexpr float SCALE  = 0.0625f;         // 1/sqrt(256)
// Scaled-Schraudolph, KS folded into per-head constants:
//   dh = (aq*KS)*x_j + (c*KS); NR-rcp(|dh|) = 2^23*log2e/|d_raw| is DIRECTLY
//   the exp bit-argument. sW accumulates RAW x_j.
constexpr float KS     = 8.2629579e-8f;   // ln2 / 2^23
constexpr float B_EXP  = 1064986816.0f;   // 2^23 * (127 - 0.0436775)
// T = 12 ln-units (validated R13-R15: absmax 0.0078).
constexpr float T0     = 1.36150e8f;      // 0.9375 * 12 * 12102203
#define RCP_MAGIC 0x7EF311C3u

// weight = bits-exp of (rcp|dh| - m), CLAMPED at B_EXP (NR mis-order -> max
// weight = correct tie; NaN corner absorbed). cvt saturates neg/NaN -> 0.
__device__ __forceinline__ float wexp_clamped(float dh, float Bh) {
    float y = __uint_as_float(RCP_MAGIC - __float_as_uint(dh));
    float w = fmaf(-fabsf(dh), fabsf(y), 2.0f);
    float f = fminf(fmaf(fabsf(y), w, Bh), B_EXP);
    unsigned u;
    asm("v_cvt_u32_f32 %0, %1" : "=v"(u) : "v"(f));
    return __uint_as_float(u);
}

// order-preserving float->uint32 (total order = float order)
__device__ __forceinline__ unsigned f2s(float f) {
    unsigned u = __float_as_uint(f);
    return (u & 0x80000000u) ? ~u : (u | 0x80000000u);
}

struct HeadCtx { float Bh; int cLo, cHi; };

// Window bounds for BOTH heads, chains HAND-INTERLEAVED: the 8-step binary
// searches are dependent divergent LDS gathers (~the kernel's dominant
// latency); interleaving head0/head1 (and then the four lo/hi searches)
// guarantees 2-4 independent chains in flight. Same ops as R15, same result.
__device__ __forceinline__ void fla_bounds2(const float* __restrict__ xsrt,
                                            float aqk0, float ck0,
                                            float aqk1, float ck1,
                                            HeadCtx& h0, HeadCtx& h1) {
    float ia0 = __builtin_amdgcn_rcpf(aqk0);
    float ia1 = __builtin_amdgcn_rcpf(aqk1);
    float xstar0 = fminf(fmaxf(-ck0 * ia0, -1e5f), 1e5f);   // NaN/inf guard
    float xstar1 = fminf(fmaxf(-ck1 * ia1, -1e5f), 1e5f);
    // two interleaved 8-step lower_bound chains
    int p0 = 0, p1 = 0;
    #pragma unroll
    for (int st = 128; st > 0; st >>= 1) {
        float a0 = xsrt[p0 + st - 1];
        float a1 = xsrt[p1 + st - 1];
        p0 += (a0 < xstar0) ? st : 0;
        p1 += (a1 < xstar1) ? st : 0;
    }
    p0 += (xsrt[p0] < xstar0) ? 1 : 0;
    p1 += (xsrt[p1] < xstar1) ? 1 : 0;
    int i1_0 = (p0 - 1 > 0) ? p0 - 1 : 0;
    int i1_1 = (p1 - 1 > 0) ? p1 - 1 : 0;
    int i2_0 = (p0 < DD - 1) ? p0 : DD - 1;
    int i2_1 = (p1 < DD - 1) ? p1 : DD - 1;
    float x2_0 = xsrt[i2_0], x2_1 = xsrt[i2_1];
    float d1_0 = fabsf(fmaf(aqk0, xsrt[i1_0], ck0));
    float d1_1 = fabsf(fmaf(aqk1, xsrt[i1_1], ck1));
    float d2_0 = fabsf(fmaf(aqk0, x2_0, ck0));
    float d2_1 = fabsf(fmaf(aqk1, x2_1, ck1));
    float dm0 = fminf(d1_0, d2_0);
    float dm1 = fminf(d1_1, d2_1);
    float ym0 = __uint_as_float(RCP_MAGIC - __float_as_uint(dm0));
    float ym1 = __uint_as_float(RCP_MAGIC - __float_as_uint(dm1));
    float m0 = fabsf(ym0) * fmaf(-dm0, fabsf(ym0), 2.0f);
    float m1 = fabsf(ym1) * fmaf(-dm1, fabsf(ym1), 2.0f);
    float mm0 = fmaf(m0, 0.9375f, -T0);       // >0 => truncation window valid
    float mm1 = fmaf(m1, 0.9375f, -T0);
    float hw0 = (mm0 > 0.f) ? __builtin_amdgcn_rcpf(mm0) * fabsf(ia0) : 3e38f;
    float hw1 = (mm1 > 0.f) ? __builtin_amdgcn_rcpf(mm1) * fabsf(ia1) : 3e38f;
    float vlo0 = xstar0 - hw0, vhi0 = fmaxf(xstar0 + hw0, x2_0);
    float vlo1 = xstar1 - hw1, vhi1 = fmaxf(xstar1 + hw1, x2_1);
    // four interleaved independent searches
    int lo0 = 0, lo1 = 0, hi0 = 0, hi1 = 0;
    #pragma unroll
    for (int st = 128; st > 0; st >>= 1) {
        float aL0 = xsrt[lo0 + st - 1];
        float aL1 = xsrt[lo1 + st - 1];
        float aH0 = xsrt[hi0 + st - 1];
        float aH1 = xsrt[hi1 + st - 1];
        lo0 += (aL0 < vlo0) ? st : 0;
        lo1 += (aL1 < vlo1) ? st : 0;
        hi0 += (aH0 < vhi0) ? st : 0;
        hi1 += (aH1 < vhi1) ? st : 0;
    }
    lo0 = (lo0 < i1_0) ? lo0 : i1_0;
    lo1 = (lo1 < i1_1) ? lo1 : i1_1;
    hi0 += (xsrt[hi0] < vhi0) ? 1 : 0;
    hi1 += (xsrt[hi1] < vhi1) ? 1 : 0;
    hi0 = (hi0 > i2_0 + 1) ? hi0 : i2_0 + 1;
    hi1 = (hi1 > i2_1 + 1) ? hi1 : i2_1 + 1;
    h0.Bh = B_EXP - m0; h0.cLo = lo0 >> 2; h0.cHi = (hi0 - 1) >> 2;
    h1.Bh = B_EXP - m1; h1.cLo = lo1 >> 2; h1.cHi = (hi1 - 1) >> 2;
}

// Chunked scan with PRECOMPUTED bounds (pipelined ds_read_b128).
__device__ __forceinline__ float2 fla_scan(const float* __restrict__ xsrt,
                                           float aqk, float ck, HeadCtx hc) {
    const float4* xs4 = reinterpret_cast<const float4*>(xsrt);
    float sE0=0.f,sE1=0.f,sE2=0.f,sE3=0.f;
    float sW0=0.f,sW1=0.f,sW2=0.f,sW3=0.f;
    #pragma unroll 2
    for (int ci = hc.cLo; ci <= hc.cHi; ++ci) {
        float4 xj = xs4[ci];
        float e0 = wexp_clamped(fmaf(aqk, xj.x, ck), hc.Bh);
        float e1 = wexp_clamped(fmaf(aqk, xj.y, ck), hc.Bh);
        float e2 = wexp_clamped(fmaf(aqk, xj.z, ck), hc.Bh);
        float e3 = wexp_clamped(fmaf(aqk, xj.w, ck), hc.Bh);
        sE0 += e0; sW0 = fmaf(e0, xj.x, sW0);
        sE1 += e1; sW1 = fmaf(e1, xj.y, sW1);
        sE2 += e2; sW2 = fmaf(e2, xj.z, sW2);
        sE3 += e3; sW3 = fmaf(e3, xj.w, sW3);
    }
    return make_float2((sE0+sE1)+(sE2+sE3), (sW0+sW1)+(sW2+sW3));
}

// Reduce two values across a 1024-thread block (16 waves). All threads get it.
__device__ __forceinline__ float2 block_reduce2(float a, float b, float* sc, int tid) {
    #pragma unroll
    for (int off = 32; off; off >>= 1) {
        a += __shfl_down(a, off, 64);
        b += __shfl_down(b, off, 64);
    }
    __syncthreads();                      // protect sc from previous use
    if ((tid & 63) == 0) { int w = tid >> 6; sc[w] = a; sc[16 + w] = b; }
    __syncthreads();
    const float4* s4 = reinterpret_cast<const float4*>(sc);
    float4 a0 = s4[0], a1 = s4[1], a2 = s4[2], a3 = s4[3];
    float4 b0 = s4[4], b1 = s4[5], b2 = s4[6], b3 = s4[7];
    float ra = ((a0.x+a0.y)+(a0.z+a0.w)) + ((a1.x+a1.y)+(a1.z+a1.w))
             + ((a2.x+a2.y)+(a2.z+a2.w)) + ((a3.x+a3.y)+(a3.z+a3.w));
    float rb = ((b0.x+b0.y)+(b0.z+b0.w)) + ((b1.x+b1.y)+(b1.z+b1.w))
             + ((b2.x+b2.y)+(b2.z+b2.w)) + ((b3.x+b3.y)+(b3.z+b3.w));
    return make_float2(ra, rb);
}

template<int LAST>
__global__ __launch_bounds__(1024, 8) void flann_layer(
    const float* __restrict__ x_in,     // [B, DD]
    const float* __restrict__ alphas,   // [NH, 3] this layer
    const float* __restrict__ betas,    // [NH, 3]
    const float* __restrict__ g1, const float* __restrict__ b1,   // fla LN
    const float* __restrict__ W,  const float* __restrict__ wb,   // [DD,DD], [DD]
    const float* __restrict__ g2, const float* __restrict__ b2,   // lin LN
    const float* __restrict__ outW, const float* __restrict__ outB,
    float* __restrict__ out)            // [B,DD] or [B] if LAST
{
    __shared__ __align__(16) float xorig[DD];       // original-order values
    __shared__ __align__(16) float xsrt[DD];        // key-sorted exact values
    __shared__ __align__(16) float xln[DD];
    __shared__ unsigned karr[DD];                   // sorted 32-bit keys
    __shared__ float comb[NHG][DD];                 // sort scratch, acc, GEMM
    __shared__ float sc[32];

    const int tid  = threadIdx.x;
    const int i    = tid & (DD - 1);    // lane slot; orig row for epilogue
    const int hg   = tid >> 8;          // head-group 0..3 (heads 2hg, 2hg+1)
    const int bidx = blockIdx.x;

    const float* xrow = x_in + bidx * DD;
    float xv = xrow[i];                 // ORIGINAL-index value (epilogue)
    if (hg == 0) xorig[i] = xv;

    // ---- 32-bit key bitonic sort: (f2s(x) & ~0xFF) | orig_index ----
    // (8-bit mantissa truncation only permutes near-equal values; window is
    //  index-clamped & inflated -> unaffected. R15-validated.)
    {
        unsigned v = (f2s(xv) & 0xFFFFFF00u) | (unsigned)i;
        unsigned* flat = reinterpret_cast<unsigned*>(&comb[0][0]);
        #pragma unroll
        for (int k = 2; k <= DD; k <<= 1) {
            #pragma unroll
            for (int j = k >> 1; j > 0; j >>= 1) {
                unsigned p;
                if (j < 64) {
                    p = (unsigned)__shfl_xor((int)v, j, 64);
                } else {
                    flat[tid] = v;
                    __syncthreads();
                    p = flat[tid ^ j];
                    __syncthreads();
                }
                bool keepmin = (((i & j) == 0) == ((i & k) == 0));
                v = keepmin ? (v < p ? v : p) : (v > p ? v : p);
            }
        }
        if (hg == 0) {                  // lane holds rank-i key
            karr[i] = v;
            xsrt[i] = xorig[v & 0xFFu]; // exact value, sorted order
        }
        __syncthreads();
    }

    // ---- tail-fold rank assignment (dense tails -> 1 of 4 waves) ----
    const int r      = (i & 1) ? (DD - 1) - (i >> 1) : (i >> 1);
    const int idx_r  = (int)(karr[r] & 0xFFu);
    const float xr_v = xsrt[r];

    // ---- my 2 heads' params for the RANK-r context ----
    const int h0 = hg * HPT;
    const float aq0 = alphas[h0*3+0], ak0 = alphas[h0*3+1], av0 = alphas[h0*3+2];
    const float bq0 = betas [h0*3+0], bk0 = betas [h0*3+1], bv0 = betas [h0*3+2];
    const float aq1 = alphas[h0*3+3], ak1 = alphas[h0*3+4], av1 = alphas[h0*3+5];
    const float bq1 = betas [h0*3+3], bk1 = betas [h0*3+4], bv1 = betas [h0*3+5];
    const float aqk0 = aq0 * KS, aqk1 = aq1 * KS;
    const float ck0  = (bq0 - fmaf(ak0, xr_v, bk0)) * KS;
    const float ck1  = (bq1 - fmaf(ak1, xr_v, bk1)) * KS;

    // interleaved bounds for BOTH heads, then both scans
    HeadCtx hc0, hc1;
    fla_bounds2(xsrt, aqk0, ck0, aqk1, ck1, hc0, hc1);
    float2 s0 = fla_scan(xsrt, aqk0, ck0, hc0);
    float2 s1 = fla_scan(xsrt, aqk1, ck1, hc1);

    // sW in RAW x units -> no rescale. 1/sE via magic + 2 NR (~1e-6 rel).
    float yE0 = __uint_as_float(RCP_MAGIC - __float_as_uint(s0.x));
    float rE0 = fabsf(yE0) * fmaf(-s0.x, fabsf(yE0), 2.0f);
    rE0 = rE0 * fmaf(-s0.x, rE0, 2.0f);
    float yE1 = __uint_as_float(RCP_MAGIC - __float_as_uint(s1.x));
    float rE1 = fabsf(yE1) * fmaf(-s1.x, fabsf(yE1), 2.0f);
    rE1 = rE1 * fmaf(-s1.x, rE1, 2.0f);
    float accp = fmaf(av0, s0.y, bv0 * s0.x) * rE0
               + fmaf(av1, s1.y, bv1 * s1.x) * rE1;
    __syncthreads();                    // comb's sort-scratch use is done
    comb[hg][idx_r] = accp;             // scatter back to ORIGINAL index
    __syncthreads();

    // ---- combine head-groups, residual + ReLU (hg 0 only, original i) ----
    float xr = 0.f;
    if (hg == 0) {
        float acc = (comb[0][i] + comb[1][i]) + (comb[2][i] + comb[3][i]);
        xr = fmaxf(fmaf(SCALE, acc, xv), 0.f);
    }

    // ---------------- LayerNorm 1 (hg!=0 contributes zeros) -----------------
    float2 rr = block_reduce2(xr, xr * xr, sc, tid);
    float mu  = rr.x * (1.f / DD);
    float var = rr.y * (1.f / DD) - mu * mu;
    if (hg == 0) {
        float xn = (xr - mu) * __builtin_amdgcn_rsqf(var + LN_EPS);
        xln[i] = fmaf(xn, g1[i], b1[i]);
    }
    __syncthreads();

    // ---------------- Linear: d-range split 4 ways across hg ----------------
    const float4* xl4 = reinterpret_cast<const float4*>(xln);
    float ga0 = (hg == 0) ? wb[i] : 0.f, ga1 = 0.f, ga2 = 0.f, ga3 = 0.f;
    #pragma unroll 4
    for (int d4 = 0; d4 < DD/16; ++d4) {
        int g4 = hg * (DD/16) + d4;
        float4 xd = xl4[g4];
        int dr = 4 * g4;
        ga0 = fmaf(xd.x, W[(dr + 0) * DD + i], ga0);   // coalesced in i
        ga1 = fmaf(xd.y, W[(dr + 1) * DD + i], ga1);
        ga2 = fmaf(xd.z, W[(dr + 2) * DD + i], ga2);
        ga3 = fmaf(xd.w, W[(dr + 3) * DD + i], ga3);
    }
    comb[hg][i] = (ga0 + ga1) + (ga2 + ga3);
    __syncthreads();

    float gv = 0.f;
    if (hg == 0)
        gv = fmaxf((comb[0][i] + comb[1][i]) + (comb[2][i] + comb[3][i]), 0.f);

    // ---------------- LayerNorm 2 ----------------
    rr = block_reduce2(gv, gv * gv, sc, tid);
    mu  = rr.x * (1.f / DD);
    var = rr.y * (1.f / DD) - mu * mu;
    float xo = 0.f;
    if (hg == 0)
        xo = fmaf((gv - mu) * __builtin_amdgcn_rsqf(var + LN_EPS), g2[i], b2[i]);

    if (!LAST) {
        if (hg == 0) out[bidx * DD + i] = xo;
    } else {
        float pr = (hg == 0) ? xo * outW[i] : 0.f;
        float2 p = block_reduce2(pr, 0.f, sc, tid);
        if (tid == 0) out[bidx] = p.x + outB[0];
    }
}

extern "C" void kernel_launch(void* const* d_in, const int* in_sizes, int n_in,
                              void* d_out, int out_size, void* d_ws, size_t ws_size,
                              hipStream_t stream) {
    const float* x      = (const float*)d_in[0];
    const float* alphas = (const float*)d_in[1];   // [L, NH, 3]
    const float* betas  = (const float*)d_in[2];   // [L, NH, 3]
    const float* flag   = (const float*)d_in[3];   // [L, DD]
    const float* flab   = (const float*)d_in[4];
    const float* linW   = (const float*)d_in[5];   // [L, DD, DD]
    const float* linb   = (const float*)d_in[6];   // [L, DD]
    const float* ling   = (const float*)d_in[7];
    const float* linb2  = (const float*)d_in[8];
    const float* outW   = (const float*)d_in[9];   // [DD]
    const float* outB   = (const float*)d_in[10];  // [1]

    const int B = in_sizes[0] / DD;
    float* ws   = (float*)d_ws;        // [B, DD] intermediate
    float* outp = (float*)d_out;       // [B]

    dim3 grid(B), block(1024);
    // layer 0: x -> ws
    flann_layer<0><<<grid, block, 0, stream>>>(
        x, alphas, betas, flag, flab, linW, linb, ling, linb2,
        nullptr, nullptr, ws);
    // layer 1 (+ fused final projection): ws -> out
    flann_layer<1><<<grid, block, 0, stream>>>(
        ws, alphas + NH*3, betas + NH*3, flag + DD, flab + DD,
        linW + DD*DD, linb + DD, ling + DD, linb2 + DD,
        outW, outB, outp);
}